// Round 3
// baseline (48.384 us; speedup 1.0000x reference)
//
#include <hip/hip_runtime.h>
#include <hip/hip_bf16.h>

// DomainBatchNorm: out[b,f] = x[b,f] * scale[d(b),f] + shift[d(b),f]
//   k1 (tiny, ~free under graph replay): fold scale/shift into d_ws (64 KB, L2-resident)
//   k2: wave-per-row apply with EXPLICIT load hoisting:
//       - 4 x-loads (HBM) issued first, before the mask->domain dependent chain
//       - then 8 param loads (L2-hit)
//       - then 4 fma + 4 nt stores
//       Goal: ~12 outstanding vector loads per wave (R1 had VGPR=16 -> ~1-2).

#define F_DIM 1024
#define D_DIM 8
#define EPSV  1e-5f

typedef float f4 __attribute__((ext_vector_type(4)));

__global__ __launch_bounds__(256) void dbn_fold(
    const f4* __restrict__ gammas, const f4* __restrict__ betas,
    const f4* __restrict__ means,  const f4* __restrict__ vars,
    f4* __restrict__ scale, f4* __restrict__ shift)
{
    const int i = blockIdx.x * 256 + threadIdx.x;   // 0 .. 2047
    if (i >= D_DIM * (F_DIM / 4)) return;
    f4 g = gammas[i], b = betas[i], m = means[i], v = vars[i];
    f4 s, h;
    s.x = g.x * rsqrtf(v.x + EPSV); h.x = fmaf(-m.x, s.x, b.x);
    s.y = g.y * rsqrtf(v.y + EPSV); h.y = fmaf(-m.y, s.y, b.y);
    s.z = g.z * rsqrtf(v.z + EPSV); h.z = fmaf(-m.z, s.z, b.z);
    s.w = g.w * rsqrtf(v.w + EPSV); h.w = fmaf(-m.w, s.w, b.w);
    scale[i] = s; shift[i] = h;
}

// One wave per row, 4 waves (rows) per block. Lane l covers float4 columns
// l, l+64, l+128, l+192 (16B/lane, fully coalesced 1KB/wave per segment).
__global__ __launch_bounds__(256) void dbn_apply(
    const f4* __restrict__ x, const float* __restrict__ mask,
    const f4* __restrict__ scale, const f4* __restrict__ shift,
    f4* __restrict__ out, int B)
{
    const int wave = threadIdx.x >> 6;
    const int lane = threadIdx.x & 63;
    const int row  = (blockIdx.x << 2) | wave;
    if (row >= B) return;  // wave-uniform

    const f4* __restrict__ xr = x + (size_t)row * (F_DIM / 4);

    // Issue the 4 HBM x-loads immediately — they do not depend on the mask.
    const int c0 = lane, c1 = lane + 64, c2 = lane + 128, c3 = lane + 192;
    f4 x0 = xr[c0];
    f4 x1 = xr[c1];
    f4 x2 = xr[c2];
    f4 x3 = xr[c3];

    // Domain resolve (dependent chain) overlaps with x-loads in flight.
    float mv = (lane < D_DIM) ? mask[(size_t)row * D_DIM + lane] : 0.0f;
    unsigned long long bal = __ballot(mv > 0.5f);
    const int d = __ffsll(bal) - 1;

    const f4* __restrict__ sc = scale + (size_t)d * (F_DIM / 4);
    const f4* __restrict__ sh = shift + (size_t)d * (F_DIM / 4);

    // 8 param loads (L2-resident, 64 KB total working set), all in flight.
    f4 s0 = sc[c0], s1 = sc[c1], s2 = sc[c2], s3 = sc[c3];
    f4 h0 = sh[c0], h1 = sh[c1], h2 = sh[c2], h3 = sh[c3];

    f4* __restrict__ orow = out + (size_t)row * (F_DIM / 4);

    f4 o0, o1, o2, o3;
    o0.x = fmaf(x0.x, s0.x, h0.x); o0.y = fmaf(x0.y, s0.y, h0.y);
    o0.z = fmaf(x0.z, s0.z, h0.z); o0.w = fmaf(x0.w, s0.w, h0.w);
    o1.x = fmaf(x1.x, s1.x, h1.x); o1.y = fmaf(x1.y, s1.y, h1.y);
    o1.z = fmaf(x1.z, s1.z, h1.z); o1.w = fmaf(x1.w, s1.w, h1.w);
    o2.x = fmaf(x2.x, s2.x, h2.x); o2.y = fmaf(x2.y, s2.y, h2.y);
    o2.z = fmaf(x2.z, s2.z, h2.z); o2.w = fmaf(x2.w, s2.w, h2.w);
    o3.x = fmaf(x3.x, s3.x, h3.x); o3.y = fmaf(x3.y, s3.y, h3.y);
    o3.z = fmaf(x3.z, s3.z, h3.z); o3.w = fmaf(x3.w, s3.w, h3.w);

    __builtin_nontemporal_store(o0, &orow[c0]);
    __builtin_nontemporal_store(o1, &orow[c1]);
    __builtin_nontemporal_store(o2, &orow[c2]);
    __builtin_nontemporal_store(o3, &orow[c3]);
}

// Fallback if ws is too small: inline fold, same hoisting idea.
__global__ __launch_bounds__(256) void dbn_apply_inline(
    const f4* __restrict__ x, const float* __restrict__ mask,
    const f4* __restrict__ gammas, const f4* __restrict__ betas,
    const f4* __restrict__ means,  const f4* __restrict__ vars,
    f4* __restrict__ out, int B)
{
    const int wave = threadIdx.x >> 6;
    const int lane = threadIdx.x & 63;
    const int row  = (blockIdx.x << 2) | wave;
    if (row >= B) return;

    const f4* __restrict__ xr = x + (size_t)row * (F_DIM / 4);
    const int c0 = lane, c1 = lane + 64, c2 = lane + 128, c3 = lane + 192;
    f4 x0 = xr[c0], x1 = xr[c1], x2 = xr[c2], x3 = xr[c3];

    float mv = (lane < D_DIM) ? mask[(size_t)row * D_DIM + lane] : 0.0f;
    unsigned long long bal = __ballot(mv > 0.5f);
    const int d = __ffsll(bal) - 1;
    const size_t pb = (size_t)d * (F_DIM / 4);

    f4* __restrict__ orow = out + (size_t)row * (F_DIM / 4);

    #pragma unroll
    for (int k = 0; k < 4; ++k) {
        const int c = lane + (k << 6);
        f4 g = gammas[pb + c], b = betas[pb + c], m = means[pb + c], v = vars[pb + c];
        f4 xv = (k == 0) ? x0 : (k == 1) ? x1 : (k == 2) ? x2 : x3;
        f4 o; float s;
        s = g.x * rsqrtf(v.x + EPSV); o.x = fmaf(xv.x, s, fmaf(-m.x, s, b.x));
        s = g.y * rsqrtf(v.y + EPSV); o.y = fmaf(xv.y, s, fmaf(-m.y, s, b.y));
        s = g.z * rsqrtf(v.z + EPSV); o.z = fmaf(xv.z, s, fmaf(-m.z, s, b.z));
        s = g.w * rsqrtf(v.w + EPSV); o.w = fmaf(xv.w, s, fmaf(-m.w, s, b.w));
        __builtin_nontemporal_store(o, &orow[c]);
    }
}

extern "C" void kernel_launch(void* const* d_in, const int* in_sizes, int n_in,
                              void* d_out, int out_size, void* d_ws, size_t ws_size,
                              hipStream_t stream) {
    const float* x    = (const float*)d_in[0];
    const float* mask = (const float*)d_in[1];
    const float* gam  = (const float*)d_in[2];
    const float* bet  = (const float*)d_in[3];
    const float* mu   = (const float*)d_in[4];
    const float* var  = (const float*)d_in[5];
    float* out        = (float*)d_out;

    const int B = in_sizes[0] / F_DIM;             // 32768
    const int grid = (B + 3) / 4;                  // 4 rows (waves) per block

    const size_t fold_bytes = (size_t)2 * D_DIM * F_DIM * sizeof(float); // 64 KB

    if (ws_size >= fold_bytes) {
        f4* scale = (f4*)d_ws;
        f4* shift = (f4*)((char*)d_ws + fold_bytes / 2);
        const int n_fold = D_DIM * (F_DIM / 4);    // 2048
        dbn_fold<<<(n_fold + 255) / 256, 256, 0, stream>>>(
            (const f4*)gam, (const f4*)bet, (const f4*)mu, (const f4*)var,
            scale, shift);
        dbn_apply<<<grid, 256, 0, stream>>>(
            (const f4*)x, mask, scale, shift, (f4*)out, B);
    } else {
        dbn_apply_inline<<<grid, 256, 0, stream>>>(
            (const f4*)x, mask, (const f4*)gam, (const f4*)bet,
            (const f4*)mu, (const f4*)var, (f4*)out, B);
    }
}